// Round 10
// baseline (169.951 us; speedup 1.0000x reference)
//
#include <hip/hip_runtime.h>
#include <hip/hip_fp16.h>

// L=8 layers, H=512, K=16 links, N_IN=512, B=8192; out = last 512 cols (fp32).
#define LAYERS 8
#define H      512
#define K      16
#define N_IN   512
#define BATCH  8192
#define R      8      // batch rows per block; 8 x f16 = 16 B -> one ds_read_b128 per gather
#define NT     512    // 8 waves/block; 64 KB LDS -> 2 blocks/CU -> 16 waves/CU
#define LDS_COLS 4096
#define PARAM_N  (LAYERS * H * K)   // 65536 params
#define SLOTS  8    // 16-B request slots per 128-B bank row

// History (dispatch time / e2e):
//  R0 baseline: 50-54us / 109.9. VGPR 64 clean.
//  R5: per-thread sort+rotate prep: conflicts only -12% (static per-thread
//    perms can't balance the wave's joint slot histogram). Dispatch 48.2-49.6
//    (best seen) but prep dispatch tax ~9us e2e.
//  R8/R9/R10: deeper same-chain read queues all regressed (55-67us).
//  R11: R=4 2x-occupancy: 74us. TLP theory dead.
//  R12: A/B split, 2x ds_read_b64: conflicts 2x (17.3M), +14us. KEY LAW:
//    counted conflict/instr (~8.2) is SIZE-INDEPENDENT -> service = floor +
//    8.2; fewest widest reads win. Conflict total = 14.1us of R0's 50; that
//    is the attackable block.
//  R13 (this): JOINT wave-level scheduling. 64 problems (wavepos x layer),
//    shared by all blocks. Prep greedy (LDS-atomic capped min-load): each
//    step, 64 lanes' slots balanced to ~8-9 vs random E[max]~12. Any valid
//    permutation is mathematically correct (same (idx,w) pairs per (l,h)) --
//    prep bugs can only cost speed. Fused = R3's proven PRESCALED path.

// ---- prep: per-(wavepos,layer) capped-greedy edge coloring ----
__global__ __launch_bounds__(64)
void ffn_sched_kernel(const int*   __restrict__ link_idx,
                      const float* __restrict__ weights,
                      int*         __restrict__ idx2,
                      float*       __restrict__ w2)
{
    __shared__ int cnt[SLOTS];
    const int lane    = threadIdx.x;          // 0..63
    const int wavepos = blockIdx.x & 7;       // wave within fused block
    const int layer   = blockIdx.x >> 3;      // 0..7
    const int t       = wavepos * 64 + lane;  // fused tid == h
    const int base    = (layer * H + t) * K;

    int idx[K]; float w[K]; int slot[K];
    #pragma unroll
    for (int k = 0; k < K; ++k) {
        idx[k]  = link_idx[base + k];
        w[k]    = weights[base + k];
        slot[k] = idx[k] & (SLOTS - 1);
    }

    unsigned rem = 0xFFFFu;                   // entries not yet scheduled
    for (int j = 0; j < K; ++j) {             // time-step j
        if (lane < SLOTS) cnt[lane] = 0;
        __syncthreads();
        int chosen = -1;
        // capped greedy: claim min-loaded slot among remaining entries;
        // cap relaxes each round -> guaranteed assignment by round 9.
        for (int iter = 0; iter < 10; ++iter) {
            if (__all(chosen >= 0)) break;
            const int cap = (iter < 8) ? (8 + iter) : (1 << 30);
            if (chosen < 0) {
                int best_e = 0, best_load = 1 << 30;
                #pragma unroll
                for (int e = 0; e < K; ++e) {
                    if (rem & (1u << e)) {
                        const int ld = cnt[slot[e]];
                        if (ld < best_load) { best_load = ld; best_e = e; }
                    }
                }
                const int old = atomicAdd(&cnt[slot[best_e]], 1);
                if (old < cap) { chosen = best_e; rem &= ~(1u << best_e); }
                else            atomicAdd(&cnt[slot[best_e]], -1);
            }
            __syncthreads();
        }
        idx2[base + j] = idx[chosen] << 4;    // pre-scaled byte offset
        w2 [base + j] = w[chosen];
        __syncthreads();
    }
}

// PRESCALED=1: idxp holds byte offsets (scheduled path).
// PRESCALED=0: idxp is raw link_idx (fallback, shift in-kernel).
template <int PRESCALED>
__global__ __launch_bounds__(NT, 2)
void ffn_fused_kernel(const float* __restrict__ x,
                      const int*   __restrict__ idxp,
                      const float* __restrict__ wp,
                      const float* __restrict__ bias,
                      float*       __restrict__ out)
{
    // vals[c*R + r] = f16 value of column c, block batch-row r.
    __shared__ __align__(16) __half vals[LDS_COLS * R];   // 65536 B

    const int tid  = threadIdx.x;
    const int row0 = blockIdx.x * R;

    // ---- Stage x rows into LDS as f16 (each thread owns one column) ----
    {
        const int c = tid;                     // NT == N_IN == 512
        float v[R];
        #pragma unroll
        for (int r = 0; r < R; ++r)
            v[r] = x[(row0 + r) * N_IN + c];   // coalesced per r
        __half2 p[R / 2];
        #pragma unroll
        for (int r = 0; r < R / 2; ++r)
            p[r] = __floats2half2_rn(v[2 * r], v[2 * r + 1]);
        *(uint4*)&vals[c * R] = *(const uint4*)p;   // one ds_write_b128
    }

    // ---- Preload layer-0 params while LDS staging drains (before barrier) ----
    int   idxA[K]; float wA[K]; float bA;
    {
        const int base = tid * K;              // l=0, h=tid
        #pragma unroll
        for (int q = 0; q < 4; ++q) {
            *(int4*)  &idxA[4 * q] = ((const int4*)  (idxp + base))[q];
            *(float4*)&wA  [4 * q] = ((const float4*)(wp   + base))[q];
        }
        if (!PRESCALED) {
            #pragma unroll
            for (int k = 0; k < K; ++k) idxA[k] <<= 4;
        }
        bA = bias[tid];
    }

    __syncthreads();

    // ---- Layers (each thread owns one h; 8 batch rows in registers) ----
    #pragma unroll
    for (int l = 0; l < LAYERS; ++l) {
        // Prefetch next layer's params under this layer's gather/FMA work.
        int idxB[K]; float wB[K]; float bB = 0.0f;
        if (l < LAYERS - 1) {
            const int nb = ((l + 1) * H + tid) * K;
            #pragma unroll
            for (int q = 0; q < 4; ++q) {
                *(int4*)  &idxB[4 * q] = ((const int4*)  (idxp + nb))[q];
                *(float4*)&wB  [4 * q] = ((const float4*)(wp   + nb))[q];
            }
            if (!PRESCALED) {
                #pragma unroll
                for (int k = 0; k < K; ++k) idxB[k] <<= 4;
            }
            bB = bias[(l + 1) * H + tid];
        }

        float acc[R];
        #pragma unroll
        for (int r = 0; r < R; ++r) acc[r] = bA;

        #pragma unroll
        for (int k = 0; k < K; ++k) {
            // one ds_read_b128 = 8 rows of the gathered column (byte offset)
            const uint4 g = *(const uint4*)((const char*)vals + idxA[k]);
            const __half2* hp = (const __half2*)&g;
            const float wk = wA[k];
            #pragma unroll
            for (int r = 0; r < R / 2; ++r) {
                const float2 f = __half22float2(hp[r]);   // folds into v_fma_mix_f32
                acc[2 * r]     = fmaf(f.x, wk, acc[2 * r]);
                acc[2 * r + 1] = fmaf(f.y, wk, acc[2 * r + 1]);
            }
        }

        // sigmoid via v_rcp_f32 (~1 ulp) instead of the ~10-instr exact divide
        #pragma unroll
        for (int r = 0; r < R; ++r)
            acc[r] = __builtin_amdgcn_rcpf(1.0f + __expf(-acc[r]));

        if (l < LAYERS - 1) {
            __half2 p[R / 2];
            #pragma unroll
            for (int r = 0; r < R / 2; ++r)
                p[r] = __floats2half2_rn(acc[2 * r], acc[2 * r + 1]);
            *(uint4*)&vals[(N_IN + l * H + tid) * R] = *(const uint4*)p;
            __syncthreads();
            // rotate prefetched params in (full unroll -> register renaming)
            #pragma unroll
            for (int k = 0; k < K; ++k) { idxA[k] = idxB[k]; wA[k] = wB[k]; }
            bA = bB;
        } else {
            // final layer: coalesced fp32 stores (lanes -> consecutive h)
            #pragma unroll
            for (int r = 0; r < R; ++r)
                out[(row0 + r) * H + tid] = acc[r];
        }
    }
}

extern "C" void kernel_launch(void* const* d_in, const int* in_sizes, int n_in,
                              void* d_out, int out_size, void* d_ws, size_t ws_size,
                              hipStream_t stream) {
    const float* x        = (const float*)d_in[0];
    const int*   link_idx = (const int*)  d_in[1];
    const float* weights  = (const float*)d_in[2];
    const float* bias     = (const float*)d_in[3];
    float*       out      = (float*)d_out;

    const size_t need = 2 * (size_t)PARAM_N * 4;   // idx2 + w2 = 512 KB

    if (d_ws != nullptr && ws_size >= need) {
        int*   idx2 = (int*)d_ws;
        float* w2   = (float*)((char*)d_ws + PARAM_N * sizeof(int));
        ffn_sched_kernel<<<dim3(64), dim3(64), 0, stream>>>(link_idx, weights, idx2, w2);
        ffn_fused_kernel<1><<<dim3(BATCH / R), dim3(NT), 0, stream>>>(x, idx2, w2, bias, out);
    } else {
        // workspace too small: proven baseline path, no global side-buffers
        ffn_fused_kernel<0><<<dim3(BATCH / R), dim3(NT), 0, stream>>>(x, link_idx, weights, bias, out);
    }
}